// Round 1
// baseline (234.081 us; speedup 1.0000x reference)
//
#include <hip/hip_runtime.h>

// GRU: B=8192 chains, T=512 steps, IN=5, H=7, fused heads.
// R7 (from R6; R5 @135us, VALUBusy 68%): fold the 4 head rows (W_m x3, W_r)
// into the pad lanes' (l=7,15) packed whh slots. Pad lanes' matvec output was
// provably dead (any dpp source landing on a pad lane has weight k==7 zeroed),
// so the head dot now rides the existing 8x pk_fma rotation chain for free:
// -8 scalar head fmas/step, -whd_rot/-bhead regs; +1 store instr (+2 ptr adds).
// Head value = accH of lanes 7/15 (biasH := head biases, accP forced 0 there).
// Layout (R4/R5, verified): 16 lanes/batch, lane l: slot0 = r row (l<8) /
// z row (l>=8), slot1 = n row (both halves); one sigmoid/lane + ror:8 swap;
// heads deferred 1 step, riding the same rotation. 2 waves/SIMD.
// DPP anchor (R3-R5 passed): row_ror:N dst[n]=src[(n-N)mod16]; position i
// holds unit (l-i)&7; weight k=(j-i)&7, k==7 -> 0 (pad killed).

namespace {
constexpr int Bn = 8192;
constexpr int Tn = 512;
constexpr int INn = 5;
constexpr int Hn = 7;
constexpr int TILE = 32;
constexpr int NTILE = Tn / TILE;         // 16
constexpr int BPB = 16;                  // batches per block (256 thr / 16)
constexpr int XSTR = 164;                // padded floats/batch in LDS
                                         // (g*164+w)%32 = (4g+w)%32: the 4
                                         // groups of a wave occupy disjoint
                                         // 4-dword bank ranges per b128
constexpr long long OFF_OR = (long long)Bn * Tn * 3;
constexpr long long OFF_HL = OFF_OR + (long long)Bn * Tn;
constexpr float LOG2E = 1.44269504088896340736f;
}

typedef float v2f __attribute__((ext_vector_type(2)));

__device__ __forceinline__ v2f pk_fma(v2f a, v2f b, v2f c) {
    return __builtin_elementwise_fma(a, b, c);
}
__device__ __forceinline__ v2f splat2(float x) { return (v2f){x, x}; }

__device__ __forceinline__ float fast_sigmoid(float x) {
    float e = __builtin_amdgcn_exp2f(-LOG2E * x);
    return __builtin_amdgcn_rcpf(1.0f + e);
}
__device__ __forceinline__ float fast_tanh(float x) {
    float e = __builtin_amdgcn_exp2f(-2.0f * LOG2E * x);
    return __builtin_amdgcn_rcpf(1.0f + e) * 2.0f - 1.0f;
}

template<int CTRL>
__device__ __forceinline__ float dppf(float v) {
    int r = __builtin_amdgcn_update_dpp(0, __builtin_bit_cast(int, v),
                                        CTRL, 0xF, 0xF, true);
    return __builtin_bit_cast(float, r);
}

__global__ __launch_bounds__(256, 2) void gru_fused_kernel(
    const float* __restrict__ x,     // [B, T, IN]
    const float* __restrict__ W_ih,  // [21, 5]
    const float* __restrict__ W_hh,  // [21, 7]
    const float* __restrict__ b_ih,  // [21]
    const float* __restrict__ b_hh,  // [21]
    const float* __restrict__ W_h0,  // [7, 1]
    const float* __restrict__ W_m,   // [3, 7]
    const float* __restrict__ b_m,   // [3]
    const float* __restrict__ W_r,   // [1, 7]
    const float* __restrict__ b_r,   // [1]
    float* __restrict__ out)
{
    __shared__ float lds_x[2][BPB * XSTR];   // 2 x 10.25 KB

    const int tid  = threadIdx.x;
    const int l    = tid & 15;           // lane within 16-lane batch group
    const int j    = l & 7;              // hidden-unit slot (7 = pad/head lane)
    const int g    = tid >> 4;           // batch slot in block
    const int b    = blockIdx.x * BPB + g;
    const int jj   = (j < 7) ? j : 6;
    const bool lo8 = ((l & 8) == 0);
    const bool hl  = (j == 7);           // head lanes: l == 7 and l == 15

    // ---- rotated, packed weights ----
    // matvec lanes (j<7): slot0 = r row (lo8) / z row (hi8), slot1 = n row.
    // head lanes (j==7): l=7  -> slot0 = W_m row0, slot1 = W_m row1
    //                    l=15 -> slot0 = W_m row2, slot1 = W_r
    const int row0 = lo8 ? jj : (Hn + jj);
    const int row1 = 2 * Hn + jj;

    v2f whh_rot[8];
    #pragma unroll
    for (int i = 0; i < 8; ++i) {
        const int k = (j - i) & 7;
        if (k < 7) {
            if (hl) {
                const float w0 = lo8 ? W_m[0 * Hn + k] : W_m[2 * Hn + k];
                const float w1 = lo8 ? W_m[1 * Hn + k] : W_r[k];
                whh_rot[i] = (v2f){w0, w1};
            } else {
                whh_rot[i] = (v2f){W_hh[row0 * Hn + k], W_hh[row1 * Hn + k]};
            }
        } else {
            whh_rot[i] = (v2f){0.0f, 0.0f};
        }
    }
    v2f wih01[INn];
    #pragma unroll
    for (int i = 0; i < INn; ++i)
        wih01[i] = hl ? (v2f){0.0f, 0.0f}
                      : (v2f){W_ih[row0 * INn + i], W_ih[row1 * INn + i]};
    const v2f biasH = hl ? (lo8 ? (v2f){b_m[0], b_m[1]}
                                : (v2f){b_m[2], b_r[0]})
                         : (v2f){b_hh[row0], b_hh[row1]};
    const v2f biasP = hl ? (v2f){0.0f, 0.0f}
                         : (v2f){b_ih[row0], b_ih[row1]};

    float hj = W_h0[jj];

    const float* xb = x + (long long)b * (Tn * INn);
    float* om  = out + (long long)b * (Tn * 3);
    float* orr = out + OFF_OR + (long long)b * Tn;

    // deferred-head store pointers: at step s store head(h_s) to index s-1.
    // hp0 <- accH[0]:  l7 -> m0 (stride 3), l15 -> m2 (stride 3)
    // hp1 <- accH[1]:  l7 -> m1 (stride 3), l15 -> r  (stride 1)
    float* hp0 = om - 3 + (lo8 ? 0 : 2);
    float* hp1 = lo8 ? (om - 2) : (orr - 1);
    const int hs1 = lo8 ? 3 : 1;

    // ---- prologue: stage tile 0 (160 floats = 80 float2 per batch) ----
    float2 stage[5];
    #pragma unroll
    for (int i = 0; i < 5; ++i)
        stage[i] = *(const float2*)(xb + 2 * (l + 16 * i));

    int cur = 0;
    for (int tl = 0; tl < NTILE; ++tl) {
        #pragma unroll
        for (int i = 0; i < 5; ++i)
            *(float2*)&lds_x[cur][g * XSTR + 2 * (l + 16 * i)] = stage[i];
        __syncthreads();

        if (tl + 1 < NTILE) {
            const float* src = xb + (tl + 1) * (TILE * INn);
            #pragma unroll
            for (int i = 0; i < 5; ++i)
                stage[i] = *(const float2*)(src + 2 * (l + 16 * i));
        }

        // x for this tile as 8 chunks of 4 steps (20 floats = 5 float4),
        // register double-buffered: chunk c+1 loads issue while c computes.
        const float4* xq = (const float4*)&lds_x[cur][g * XSTR];
        float4 xbuf[2][5];
        #pragma unroll
        for (int k = 0; k < 5; ++k) xbuf[0][k] = xq[k];

        #pragma unroll
        for (int c = 0; c < 8; ++c) {
            if (c < 7) {
                #pragma unroll
                for (int k = 0; k < 5; ++k)
                    xbuf[(c + 1) & 1][k] = xq[(c + 1) * 5 + k];
            }
            const float* xcf = (const float*)xbuf[c & 1];

            #pragma unroll
            for (int ss = 0; ss < 4; ++ss) {
                const int tt = c * 4 + ss;

                // systolic rotation, all rors independent off hj:
                // hidden matvec (packed r|z,n) and head rows (pad lanes)
                // share the same pk_fma chain.
                v2f accA = biasH;
                v2f accB = (v2f){0.0f, 0.0f};
                accA = pk_fma(whh_rot[0], splat2(hj), accA);
                {
                    float h1 = dppf<0x121>(hj);
                    accB = pk_fma(whh_rot[1], splat2(h1), accB);
                    float h2 = dppf<0x122>(hj);
                    accA = pk_fma(whh_rot[2], splat2(h2), accA);
                    float h3 = dppf<0x123>(hj);
                    accB = pk_fma(whh_rot[3], splat2(h3), accB);
                    float h4 = dppf<0x124>(hj);
                    accA = pk_fma(whh_rot[4], splat2(h4), accA);
                    float h5 = dppf<0x125>(hj);
                    accB = pk_fma(whh_rot[5], splat2(h5), accB);
                    float h6 = dppf<0x126>(hj);
                    accA = pk_fma(whh_rot[6], splat2(h6), accA);
                    float h7 = dppf<0x127>(hj);
                    accB = pk_fma(whh_rot[7], splat2(h7), accB);
                }
                v2f accH = accA + accB;          // (g0, g1) hidden-only
                                                 // head lanes: (head0, head1)

                // input projection (r multiplies hidden part only)
                v2f accP = biasP;
                #pragma unroll
                for (int i = 0; i < INn; ++i)
                    accP = pk_fma(wih01[i], splat2(xcf[5 * ss + i]), accP);

                // deferred head(h_t) -> index t-1 (guard folds away for tt>0)
                if ((tl > 0 || tt > 0) && hl) {
                    *hp0 = accH[0];
                    *hp1 = accH[1];
                }
                hp0 += 3;
                hp1 += hs1;

                // gates (head lanes compute bounded garbage; never consumed)
                float s  = fast_sigmoid(accH[0] + accP[0]);
                float sv = dppf<0x128>(s);       // row_ror:8 half-swap
                float r_val = lo8 ? s : sv;
                float z_val = lo8 ? sv : s;
                float n = fast_tanh(fmaf(r_val, accH[1], accP[1]));
                hj = n + z_val * (hj - n);       // (1-z)*n + z*h
            }
        }
        cur ^= 1;
    }

    // epilogue: head of final h (one more rotation), stored at index T-1
    {
        v2f accA = biasH;
        v2f accB = (v2f){0.0f, 0.0f};
        accA = pk_fma(whh_rot[0], splat2(hj), accA);
        accB = pk_fma(whh_rot[1], splat2(dppf<0x121>(hj)), accB);
        accA = pk_fma(whh_rot[2], splat2(dppf<0x122>(hj)), accA);
        accB = pk_fma(whh_rot[3], splat2(dppf<0x123>(hj)), accB);
        accA = pk_fma(whh_rot[4], splat2(dppf<0x124>(hj)), accA);
        accB = pk_fma(whh_rot[5], splat2(dppf<0x125>(hj)), accB);
        accA = pk_fma(whh_rot[6], splat2(dppf<0x126>(hj)), accA);
        accB = pk_fma(whh_rot[7], splat2(dppf<0x127>(hj)), accB);
        v2f accH = accA + accB;
        if (hl) {
            *hp0 = accH[0];
            *hp1 = accH[1];
        }
    }

    // h_last: [1, B, H]
    if (l < Hn) out[OFF_HL + (long long)b * Hn + l] = hj;
}

extern "C" void kernel_launch(void* const* d_in, const int* in_sizes, int n_in,
                              void* d_out, int out_size, void* d_ws, size_t ws_size,
                              hipStream_t stream) {
    const float* x    = (const float*)d_in[0];
    // d_in[1] = batch_size (scalar), unused — B compiled in
    const float* W_ih = (const float*)d_in[2];
    const float* W_hh = (const float*)d_in[3];
    const float* b_ih = (const float*)d_in[4];
    const float* b_hh = (const float*)d_in[5];
    const float* W_h0 = (const float*)d_in[6];
    const float* W_m  = (const float*)d_in[7];
    const float* b_m  = (const float*)d_in[8];
    const float* W_r  = (const float*)d_in[9];
    const float* b_r  = (const float*)d_in[10];
    float* out = (float*)d_out;

    dim3 grid(Bn / BPB);  // 512 blocks
    dim3 block(256);      // 16 batch elements x 16 lanes
    gru_fused_kernel<<<grid, block, 0, stream>>>(x, W_ih, W_hh, b_ih, b_hh,
                                                 W_h0, W_m, b_m, W_r, b_r, out);
}